// Round 5
// baseline (2180.126 us; speedup 1.0000x reference)
//
#include <hip/hip_runtime.h>
#include <hip/hip_fp16.h>
#include <math.h>
#include <stdint.h>

typedef _Float16 f16;
typedef _Float16 h8 __attribute__((ext_vector_type(8)));
typedef float f4 __attribute__((ext_vector_type(4)));

#define TSTEPS 48

#define MFMA(a,b,c) __builtin_amdgcn_mfma_f32_16x16x32_f16((a),(b),(c),0,0,0)

// branch-free gelu via A&S 7.1.26 erf approx (max abs err 1.5e-7 << f16 rounding)
__device__ __forceinline__ float gelu_f(float x) {
  float ax = fabsf(x) * 0.7071067811865475f;
  float t = __builtin_amdgcn_rcpf(1.0f + 0.3275911f * ax);
  float poly = t * (0.254829592f + t * (-0.284496736f + t * (1.421413741f +
               t * (-1.453152027f + t * 1.061405429f))));
  float e = exp2f(-ax * ax * 1.4426950408889634f);
  float er = copysignf(1.0f - poly * e, x);
  return 0.5f * x * (1.0f + er);
}

// tanh = 1 - 2/(e^{2x}+1); exp2 overflow/underflow gives correct +-1 limits
__device__ __forceinline__ float tanh_f(float x) {
  float e = exp2f(x * 2.885390081777927f);   // e^{2x}
  return 1.0f - 2.0f * __builtin_amdgcn_rcpf(e + 1.0f);
}

// ---------------- weight prep: k-slice stream  dst[(kk*N+n)*32+w] = src[(kk*32+w)*N+n]
__global__ void prep_ws(const float* __restrict__ src, f16* __restrict__ dst,
                        int Kreal, int N, int total) {
  int idx = blockIdx.x * 256 + threadIdx.x;
  if (idx >= total) return;
  int w = idx & 31;
  int n = (idx >> 5) % N;
  int kk = idx / (N * 32);
  int k = kk * 32 + w;
  dst[idx] = (f16)((k < Kreal) ? src[k * N + n] : 0.f);
}

// ---------------- feature kernel: fourier + hashgrid + z -> fp16 [B][192] ----
__global__ void feat_kernel(const float* __restrict__ x, const float* __restrict__ z,
                            const float* __restrict__ tables, const int* __restrict__ res,
                            const float* __restrict__ freqs, f16* __restrict__ featsH) {
  __shared__ f16 rowbuf[64][194];
  const int t = threadIdx.x;        // 64 threads
  const int b = blockIdx.x;
  const int i = b * 64 + t;

  float xv = x[i];
  float xn = fminf(fmaxf(xv, 0.f), 1.f);
  f16* dst = rowbuf[t];
  dst[0] = (f16)xn;
  float w2pi = 6.283185307179586f * xn;
  #pragma unroll
  for (int k = 0; k < 32; ++k) {
    float a = w2pi * freqs[k];
    float s, c;
    sincosf(a, &s, &c);
    dst[1 + k]  = (f16)s;
    dst[33 + k] = (f16)c;
  }
  #pragma unroll
  for (int l = 0; l < 8; ++l) {
    int R = res[l];
    int Rm1 = R - 1;
    float tt = xn * (float)Rm1;
    int i0 = (int)tt;
    int i1 = min(i0 + 1, Rm1);
    float w = tt - (float)i0;
    uint32_t lt = (uint32_t)(l * 19349663);
    uint32_t h0 = (((uint32_t)i0 * 73856093u) ^ lt) & 16383u;
    uint32_t h1 = (((uint32_t)i1 * 73856093u) ^ lt) & 16383u;
    const float* e0 = tables + ((size_t)l * 16384 + h0) * 8;
    const float* e1 = tables + ((size_t)l * 16384 + h1) * 8;
    #pragma unroll
    for (int e = 0; e < 8; ++e) {
      float v = e0[e] * (1.f - w) + e1[e] * w;
      dst[65 + l * 8 + e] = (f16)v;
    }
  }
  #pragma unroll
  for (int j = 0; j < 32; ++j) dst[129 + j] = (f16)z[(size_t)i * 32 + j];
  #pragma unroll
  for (int j = 161; j < 192; ++j) dst[j] = (f16)0.f;

  __syncthreads();
  uint32_t* dg = (uint32_t*)(featsH + (size_t)b * 64 * 192);
  for (int idx = t; idx < 64 * 96; idx += 64) {
    int row = idx / 96, o = idx - row * 96;
    dg[idx] = ((const uint32_t*)&rowbuf[row][0])[o];
  }
}

// ---------------- main fused kernel ----------------
// 256 blocks x 512 threads (8 waves), 2 waves/SIMD, VGPR cap 256.
// Block owns 64 rows. Wave-grid 1M x 8N:
//   GEMM1 (N=512): wave wn covers cols [64*wn,+64), folded into two 32-col halves
//   GEMM2/layers (N=256): wave wn covers cols [32*wn,+32)
// Wf2 B-operand is WAVE-STATIONARY -> preloaded into 128 VGPRs (32 x h8) before
// the t-loop: GEMM2 runs with zero weight loads. Wf1 streamed with a 4-slot
// distance-3 register rotation that wraps to next step's addresses (stream is
// t-invariant), so its tail loads soak across the whole GEMM2 phase.
// LDS: hB [0,32K) fp16 h tile [64][256] stride 512B (XOR-swizzled)
//      uB [32K,96K) fp16 u tile [64][512] stride 1024B (feats staging reuses)
__global__ __launch_bounds__(512, 2) void fractal_main(
    const f16* __restrict__ featsH,
    const f16* __restrict__ W1s, const f16* __restrict__ W2s,
    const f16* __restrict__ Wos,
    const f16* __restrict__ Wf1s, const f16* __restrict__ Wf2s,
    const float* __restrict__ b1, const float* __restrict__ b2,
    const float* __restrict__ bf1, const float* __restrict__ bf2,
    const float* __restrict__ bo,
    float* __restrict__ out) {
  extern __shared__ char smem[];
  char* hB = smem;
  char* uB = smem + 32768;

  const int tid = threadIdx.x;
  const int wn  = tid >> 6;          // 0..7
  const int ln  = tid & 63;
  const int r   = ln & 15;
  const int g   = ln >> 4;
  const int sw  = (r & 7) << 4;
  const int g16 = g * 16;
  const int row0 = blockIdx.x * 64;

  const int cH = 32 * wn + r;        // wave's HID-col base (+16*nf)
  float b1r[2], b2r[2], bf2r[2], bor[2], bf1r[4];
  #pragma unroll
  for (int nf = 0; nf < 2; ++nf) {
    b1r[nf] = b1[cH + 16 * nf]; b2r[nf] = b2[cH + 16 * nf];
    bf2r[nf] = bf2[cH + 16 * nf]; bor[nf] = bo[cH + 16 * nf];
  }
  #pragma unroll
  for (int nf = 0; nf < 4; ++nf) bf1r[nf] = bf1[64 * wn + 16 * nf + r];

  // ---- stage feats tile into uB (swizzled, row stride 384B) ----
  {
    const char* src = (const char*)featsH + (size_t)row0 * 384;
    for (int i = tid; i < 6144; i += 512) {
      int row = i / 96;
      int off = (i - row * 96) * 4;
      uint32_t v = *(const uint32_t*)(src + (size_t)i * 4);
      *(uint32_t*)(uB + row * 384 + (off ^ ((row & 7) << 4))) = v;
    }
  }
  __syncthreads();

  f4 m[4][2];   // master h (f32), rows 16*mf+g*4+j, cols cH+16*nf
  const f4 zf = {0.f, 0.f, 0.f, 0.f};

  // ---- layer 1: feats @ W1 ----
  {
    f4 acc[4][2];
    #pragma unroll
    for (int mf = 0; mf < 4; ++mf)
      #pragma unroll
      for (int nf = 0; nf < 2; ++nf) acc[mf][nf] = zf;
    #pragma unroll
    for (int kk = 0; kk < 6; ++kk) {
      h8 a[4], bb[2];
      #pragma unroll
      for (int mf = 0; mf < 4; ++mf)
        a[mf] = *(const h8*)(uB + (16 * mf + r) * 384 + ((kk * 64 + g16) ^ sw));
      #pragma unroll
      for (int nf = 0; nf < 2; ++nf)
        bb[nf] = *(const h8*)(W1s + ((kk * 256 + cH + 16 * nf) << 5) + g * 8);
      #pragma unroll
      for (int mf = 0; mf < 4; ++mf)
        #pragma unroll
        for (int nf = 0; nf < 2; ++nf)
          acc[mf][nf] = MFMA(a[mf], bb[nf], acc[mf][nf]);
    }
    #pragma unroll
    for (int mf = 0; mf < 4; ++mf)
      #pragma unroll
      for (int nf = 0; nf < 2; ++nf)
        #pragma unroll
        for (int j = 0; j < 4; ++j)
          m[mf][nf][j] = gelu_f(acc[mf][nf][j] + b1r[nf]);
  }
  #pragma unroll
  for (int mf = 0; mf < 4; ++mf)
    #pragma unroll
    for (int nf = 0; nf < 2; ++nf)
      #pragma unroll
      for (int j = 0; j < 4; ++j) {
        int row = 16 * mf + g * 4 + j;
        int col = cH + 16 * nf;
        *(f16*)(hB + row * 512 + ((col * 2) ^ ((row & 7) << 4))) = (f16)m[mf][nf][j];
      }
  __syncthreads();

  // ---- layer 2: h @ W2 ----
  {
    f4 acc[4][2];
    #pragma unroll
    for (int mf = 0; mf < 4; ++mf)
      #pragma unroll
      for (int nf = 0; nf < 2; ++nf) acc[mf][nf] = zf;
    #pragma unroll
    for (int kk = 0; kk < 8; ++kk) {
      h8 a[4], bb[2];
      #pragma unroll
      for (int mf = 0; mf < 4; ++mf)
        a[mf] = *(const h8*)(hB + (16 * mf + r) * 512 + ((kk * 64 + g16) ^ sw));
      #pragma unroll
      for (int nf = 0; nf < 2; ++nf)
        bb[nf] = *(const h8*)(W2s + ((kk * 256 + cH + 16 * nf) << 5) + g * 8);
      #pragma unroll
      for (int mf = 0; mf < 4; ++mf)
        #pragma unroll
        for (int nf = 0; nf < 2; ++nf)
          acc[mf][nf] = MFMA(a[mf], bb[nf], acc[mf][nf]);
    }
    #pragma unroll
    for (int mf = 0; mf < 4; ++mf)
      #pragma unroll
      for (int nf = 0; nf < 2; ++nf)
        #pragma unroll
        for (int j = 0; j < 4; ++j)
          m[mf][nf][j] = gelu_f(acc[mf][nf][j] + b2r[nf]);
  }
  __syncthreads();   // all waves done reading old hB
  #pragma unroll
  for (int mf = 0; mf < 4; ++mf)
    #pragma unroll
    for (int nf = 0; nf < 2; ++nf)
      #pragma unroll
      for (int j = 0; j < 4; ++j) {
        int row = 16 * mf + g * 4 + j;
        int col = cH + 16 * nf;
        *(f16*)(hB + row * 512 + ((col * 2) ^ ((row & 7) << 4))) = (f16)m[mf][nf][j];
      }
  __syncthreads();

  // ---- preload wave-stationary Wf2 slice into registers (32 x h8 = 128 VGPR) ----
  h8 wB[16][2];
  #pragma unroll
  for (int kk = 0; kk < 16; ++kk)
    #pragma unroll
    for (int nf = 0; nf < 2; ++nf)
      wB[kk][nf] = *(const h8*)(Wf2s + ((kk * 256 + cH + 16 * nf) << 5) + g * 8);

  // ---- prime Wf1 rotation (distance-3, ring of 4), flat index i = q*8+kk ----
  h8 pf[4][2];
  #pragma unroll
  for (int p = 0; p < 3; ++p)
    #pragma unroll
    for (int nf = 0; nf < 2; ++nf)
      pf[p][nf] = *(const h8*)(Wf1s +
        (((p & 7) * 512 + 64 * wn + 32 * (p >> 3) + 16 * nf + r) << 5) + g * 8);

  // ---- 48 fractal steps ----
  for (int t = 0; t < TSTEPS; ++t) {
    // GEMM1: u = h @ Wf1 (N=512), wave cols [64*wn,+64) in two 32-col halves.
    #pragma unroll
    for (int q = 0; q < 2; ++q) {
      f4 acc[4][2];
      #pragma unroll
      for (int mf = 0; mf < 4; ++mf)
        #pragma unroll
        for (int nf = 0; nf < 2; ++nf) acc[mf][nf] = zf;
      #pragma unroll
      for (int kk = 0; kk < 8; ++kk) {
        const int i = q * 8 + kk;
        const int ip = (i + 3) & 15;           // prefetch target (wraps to next t)
        #pragma unroll
        for (int nf = 0; nf < 2; ++nf)
          pf[(i + 3) & 3][nf] = *(const h8*)(Wf1s +
            (((ip & 7) * 512 + 64 * wn + 32 * (ip >> 3) + 16 * nf + r) << 5) + g * 8);
        h8 a[4];
        #pragma unroll
        for (int mf = 0; mf < 4; ++mf)
          a[mf] = *(const h8*)(hB + (16 * mf + r) * 512 + ((kk * 64 + g16) ^ sw));
        #pragma unroll
        for (int mf = 0; mf < 4; ++mf)
          #pragma unroll
          for (int nf = 0; nf < 2; ++nf)
            acc[mf][nf] = MFMA(a[mf], pf[i & 3][nf], acc[mf][nf]);
      }
      // epilogue half-q: gelu -> uB cols 64*wn+32*q+16*nf+r
      #pragma unroll
      for (int mf = 0; mf < 4; ++mf)
        #pragma unroll
        for (int nf = 0; nf < 2; ++nf)
          #pragma unroll
          for (int j = 0; j < 4; ++j) {
            float gv = gelu_f(acc[mf][nf][j] + bf1r[q * 2 + nf]);
            int row = 16 * mf + g * 4 + j;
            int col = 64 * wn + 32 * q + 16 * nf + r;
            *(f16*)(uB + row * 1024 + ((col * 2) ^ ((row & 7) << 4))) = (f16)gv;
          }
    }
    __syncthreads();

    // GEMM2: h' = tanh(u @ Wf2) (N=256, K=512) — B entirely in registers.
    f4 a2[4][2];
    #pragma unroll
    for (int mf = 0; mf < 4; ++mf)
      #pragma unroll
      for (int nf = 0; nf < 2; ++nf) a2[mf][nf] = zf;
    #pragma unroll
    for (int kk = 0; kk < 16; ++kk) {
      h8 a[4];
      #pragma unroll
      for (int mf = 0; mf < 4; ++mf)
        a[mf] = *(const h8*)(uB + (16 * mf + r) * 1024 + ((kk * 64 + g16) ^ sw));
      #pragma unroll
      for (int mf = 0; mf < 4; ++mf)
        #pragma unroll
        for (int nf = 0; nf < 2; ++nf)
          a2[mf][nf] = MFMA(a[mf], wB[kk][nf], a2[mf][nf]);
    }
    // epilogue: tanh, mix, write hB
    #pragma unroll
    for (int mf = 0; mf < 4; ++mf)
      #pragma unroll
      for (int nf = 0; nf < 2; ++nf)
        #pragma unroll
        for (int j = 0; j < 4; ++j) {
          float u = tanh_f(a2[mf][nf][j] + bf2r[nf]);
          float hn = 0.5f * (m[mf][nf][j] + u);
          m[mf][nf][j] = hn;
          int row = 16 * mf + g * 4 + j;
          int col = cH + 16 * nf;
          *(f16*)(hB + row * 512 + ((col * 2) ^ ((row & 7) << 4))) = (f16)hn;
        }
    __syncthreads();
  }

  // ---- final: out = h @ Wo + bo ----
  {
    f4 acc[4][2];
    #pragma unroll
    for (int mf = 0; mf < 4; ++mf)
      #pragma unroll
      for (int nf = 0; nf < 2; ++nf) acc[mf][nf] = zf;
    #pragma unroll
    for (int kk = 0; kk < 8; ++kk) {
      h8 a[4], bb[2];
      #pragma unroll
      for (int mf = 0; mf < 4; ++mf)
        a[mf] = *(const h8*)(hB + (16 * mf + r) * 512 + ((kk * 64 + g16) ^ sw));
      #pragma unroll
      for (int nf = 0; nf < 2; ++nf)
        bb[nf] = *(const h8*)(Wos + ((kk * 256 + cH + 16 * nf) << 5) + g * 8);
      #pragma unroll
      for (int mf = 0; mf < 4; ++mf)
        #pragma unroll
        for (int nf = 0; nf < 2; ++nf)
          acc[mf][nf] = MFMA(a[mf], bb[nf], acc[mf][nf]);
    }
    #pragma unroll
    for (int mf = 0; mf < 4; ++mf)
      #pragma unroll
      for (int nf = 0; nf < 2; ++nf)
        #pragma unroll
        for (int j = 0; j < 4; ++j) {
          int row = row0 + 16 * mf + g * 4 + j;
          int col = cH + 16 * nf;
          out[(size_t)row * 256 + col] = acc[mf][nf][j] + bor[nf];
        }
  }
}

// ---------------- host launch ----------------
extern "C" void kernel_launch(void* const* d_in, const int* in_sizes, int n_in,
                              void* d_out, int out_size, void* d_ws, size_t ws_size,
                              hipStream_t stream) {
  const float* x      = (const float*)d_in[0];
  const float* z      = (const float*)d_in[1];
  const float* tables = (const float*)d_in[2];
  const float* W1     = (const float*)d_in[3];
  const float* b1     = (const float*)d_in[4];
  const float* W2     = (const float*)d_in[5];
  const float* b2     = (const float*)d_in[6];
  const float* Wf1    = (const float*)d_in[7];
  const float* bf1    = (const float*)d_in[8];
  const float* Wf2    = (const float*)d_in[9];
  const float* bf2    = (const float*)d_in[10];
  const float* Wo     = (const float*)d_in[11];
  const float* bo     = (const float*)d_in[12];
  const int*   res    = (const int*)d_in[13];
  const float* freqs  = (const float*)d_in[14];
  float* out = (float*)d_out;

  char* ws = (char*)d_ws;
  f16* featsH = (f16*)(ws);                 // 16384*192*2 = 6291456
  f16* W1s    = (f16*)(ws + 6291456);       // 6*256*32*2  = 98304
  f16* W2s    = (f16*)(ws + 6389760);       // 8*256*32*2  = 131072
  f16* Wos    = (f16*)(ws + 6520832);       // 8*256*32*2  = 131072
  f16* Wf1s   = (f16*)(ws + 6651904);       // 8*512*32*2  = 262144
  f16* Wf2s   = (f16*)(ws + 6914048);       // 16*256*32*2 = 262144

  prep_ws<<<192, 256, 0, stream>>>(W1,  W1s,  161, 256, 6  * 256 * 32);
  prep_ws<<<256, 256, 0, stream>>>(W2,  W2s,  256, 256, 8  * 256 * 32);
  prep_ws<<<256, 256, 0, stream>>>(Wo,  Wos,  256, 256, 8  * 256 * 32);
  prep_ws<<<512, 256, 0, stream>>>(Wf1, Wf1s, 256, 512, 8  * 512 * 32);
  prep_ws<<<512, 256, 0, stream>>>(Wf2, Wf2s, 512, 256, 16 * 256 * 32);
  feat_kernel<<<256, 64, 0, stream>>>(x, z, tables, res, freqs, featsH);

  (void)hipFuncSetAttribute((const void*)fractal_main,
                            hipFuncAttributeMaxDynamicSharedMemorySize, 98304);
  fractal_main<<<256, 512, 98304, stream>>>(featsH, W1s, W2s, Wos, Wf1s, Wf2s,
                                            b1, b2, bf1, bf2, bo, out);
}

// Round 6
// 1981.837 us; speedup vs baseline: 1.1001x; 1.1001x over previous
//
#include <hip/hip_runtime.h>
#include <hip/hip_fp16.h>
#include <math.h>
#include <stdint.h>

typedef _Float16 f16;
typedef _Float16 h8 __attribute__((ext_vector_type(8)));
typedef float f4 __attribute__((ext_vector_type(4)));

#define TSTEPS 48

#define MFMA(a,b,c) __builtin_amdgcn_mfma_f32_16x16x32_f16((a),(b),(c),0,0,0)

__device__ __forceinline__ float gelu_f(float x) {
  float ax = fabsf(x) * 0.7071067811865475f;
  float t = __builtin_amdgcn_rcpf(1.0f + 0.3275911f * ax);
  float poly = t * (0.254829592f + t * (-0.284496736f + t * (1.421413741f +
               t * (-1.453152027f + t * 1.061405429f))));
  float e = exp2f(-ax * ax * 1.4426950408889634f);
  float er = copysignf(1.0f - poly * e, x);
  return 0.5f * x * (1.0f + er);
}

__device__ __forceinline__ float tanh_f(float x) {
  float e = exp2f(x * 2.885390081777927f);
  return 1.0f - 2.0f * __builtin_amdgcn_rcpf(e + 1.0f);
}

__device__ __forceinline__ void gload_lds16(const void* g, void* l) {
  __builtin_amdgcn_global_load_lds(
      (const __attribute__((address_space(1))) void*)g,
      (__attribute__((address_space(3))) void*)l, 16, 0, 0);
}

// ---------------- weight prep: k-slice stream  dst[(kk*N+n)*32+w] = src[(kk*32+w)*N+n]
__global__ void prep_ws(const float* __restrict__ src, f16* __restrict__ dst,
                        int Kreal, int N, int total) {
  int idx = blockIdx.x * 256 + threadIdx.x;
  if (idx >= total) return;
  int w = idx & 31;
  int n = (idx >> 5) % N;
  int kk = idx / (N * 32);
  int k = kk * 32 + w;
  dst[idx] = (f16)((k < Kreal) ? src[k * N + n] : 0.f);
}

// ---------------- Wf1 lane-linear fragment stream ----------------
// frag (kk, cf): 16 cols c0=cf*16, k-slice kk*32..+32. Lane ln (r=ln&15,g=ln>>4)
// holds 8 f16 at dst[fragid*512 + ln*8 + e] = Wf1[kk*32+g*8+e][c0 + r].
__global__ void prep_wf1lin(const float* __restrict__ src, f16* __restrict__ dst) {
  int idx = blockIdx.x * 256 + threadIdx.x;   // 131072 elems
  if (idx >= 131072) return;
  int fragid = idx >> 9;        // 0..255
  int within = idx & 511;
  int ln = within >> 3, e = within & 7;
  int kk = fragid >> 5, cf = fragid & 31;
  int k = kk * 32 + (ln >> 4) * 8 + e;
  int n = cf * 16 + (ln & 15);
  dst[idx] = (f16)src[k * 512 + n];
}

// ---------------- feature kernel: fourier + hashgrid + z -> fp16 [B][192] ----
__global__ void feat_kernel(const float* __restrict__ x, const float* __restrict__ z,
                            const float* __restrict__ tables, const int* __restrict__ res,
                            const float* __restrict__ freqs, f16* __restrict__ featsH) {
  __shared__ f16 rowbuf[64][194];
  const int t = threadIdx.x;        // 64 threads
  const int b = blockIdx.x;
  const int i = b * 64 + t;

  float xv = x[i];
  float xn = fminf(fmaxf(xv, 0.f), 1.f);
  f16* dst = rowbuf[t];
  dst[0] = (f16)xn;
  float w2pi = 6.283185307179586f * xn;
  #pragma unroll
  for (int k = 0; k < 32; ++k) {
    float a = w2pi * freqs[k];
    float s, c;
    sincosf(a, &s, &c);
    dst[1 + k]  = (f16)s;
    dst[33 + k] = (f16)c;
  }
  #pragma unroll
  for (int l = 0; l < 8; ++l) {
    int R = res[l];
    int Rm1 = R - 1;
    float tt = xn * (float)Rm1;
    int i0 = (int)tt;
    int i1 = min(i0 + 1, Rm1);
    float w = tt - (float)i0;
    uint32_t lt = (uint32_t)(l * 19349663);
    uint32_t h0 = (((uint32_t)i0 * 73856093u) ^ lt) & 16383u;
    uint32_t h1 = (((uint32_t)i1 * 73856093u) ^ lt) & 16383u;
    const float* e0 = tables + ((size_t)l * 16384 + h0) * 8;
    const float* e1 = tables + ((size_t)l * 16384 + h1) * 8;
    #pragma unroll
    for (int e = 0; e < 8; ++e) {
      float v = e0[e] * (1.f - w) + e1[e] * w;
      dst[65 + l * 8 + e] = (f16)v;
    }
  }
  #pragma unroll
  for (int j = 0; j < 32; ++j) dst[129 + j] = (f16)z[(size_t)i * 32 + j];
  #pragma unroll
  for (int j = 161; j < 192; ++j) dst[j] = (f16)0.f;

  __syncthreads();
  uint32_t* dg = (uint32_t*)(featsH + (size_t)b * 64 * 192);
  for (int idx = t; idx < 64 * 96; idx += 64) {
    int row = idx / 96, o = idx - row * 96;
    dg[idx] = ((const uint32_t*)&rowbuf[row][0])[o];
  }
}

// ---------------- main fused kernel ----------------
// 256 blocks x 512 threads (8 waves), 1 block/CU, VGPR cap 256.
// Wf2 slice per wave (32 cols x 512 K = 32KB = 128 VGPR) is loaded ONCE via
// LDS staging (uB chunks) -> ds_read -> registers. LDS-sourced => compiler
// cannot rematerialize from global; uB is overwritten each step.
// Wf1 streamed lane-linear with ring-4 distance-3 register prefetch whose ring
// wraps across steps (addresses t-invariant).
__global__ __launch_bounds__(512, 2) void fractal_main(
    const f16* __restrict__ featsH,
    const f16* __restrict__ W1s, const f16* __restrict__ W2s,
    const f16* __restrict__ Wos,
    const f16* __restrict__ Wf1s, const f16* __restrict__ Wf2s,
    const float* __restrict__ b1, const float* __restrict__ b2,
    const float* __restrict__ bf1, const float* __restrict__ bf2,
    const float* __restrict__ bo,
    float* __restrict__ out) {
  extern __shared__ char smem[];
  char* hB = smem;            // 32KB
  char* uB = smem + 32768;    // 64KB

  const int tid = threadIdx.x;
  const int wn  = tid >> 6;          // 0..7
  const int ln  = tid & 63;
  const int r   = ln & 15;
  const int g   = ln >> 4;
  const int sw  = (r & 7) << 4;
  const int g16 = g * 16;
  const int row0 = blockIdx.x * 64;

  const int cH = 32 * wn + r;        // wave's HID-col base (+16*nf)
  float b1r[2], b2r[2], bf2r[2], bor[2], bf1r[4];
  #pragma unroll
  for (int nf = 0; nf < 2; ++nf) {
    b1r[nf] = b1[cH + 16 * nf]; b2r[nf] = b2[cH + 16 * nf];
    bf2r[nf] = bf2[cH + 16 * nf]; bor[nf] = bo[cH + 16 * nf];
  }
  #pragma unroll
  for (int nf = 0; nf < 4; ++nf) bf1r[nf] = bf1[64 * wn + 16 * nf + r];

  // ---- stage feats tile into uB (swizzled, row stride 384B) ----
  {
    const char* src = (const char*)featsH + (size_t)row0 * 384;
    for (int i = tid; i < 6144; i += 512) {
      int row = i / 96;
      int off = (i - row * 96) * 4;
      uint32_t v = *(const uint32_t*)(src + (size_t)i * 4);
      *(uint32_t*)(uB + row * 384 + (off ^ ((row & 7) << 4))) = v;
    }
  }
  __syncthreads();

  f4 m[4][2];   // master h (f32), rows 16*mf+g*4+j, cols cH+16*nf
  const f4 zf = {0.f, 0.f, 0.f, 0.f};

  // ---- layer 1: feats @ W1 ----
  {
    f4 acc[4][2];
    #pragma unroll
    for (int mf = 0; mf < 4; ++mf)
      #pragma unroll
      for (int nf = 0; nf < 2; ++nf) acc[mf][nf] = zf;
    #pragma unroll
    for (int kk = 0; kk < 6; ++kk) {
      h8 bb[2];
      #pragma unroll
      for (int nf = 0; nf < 2; ++nf)
        bb[nf] = *(const h8*)(W1s + ((kk * 256 + cH + 16 * nf) << 5) + g * 8);
      #pragma unroll
      for (int mf = 0; mf < 4; ++mf) {
        h8 a = *(const h8*)(uB + (16 * mf + r) * 384 + ((kk * 64 + g16) ^ sw));
        #pragma unroll
        for (int nf = 0; nf < 2; ++nf)
          acc[mf][nf] = MFMA(a, bb[nf], acc[mf][nf]);
      }
    }
    #pragma unroll
    for (int mf = 0; mf < 4; ++mf)
      #pragma unroll
      for (int nf = 0; nf < 2; ++nf)
        #pragma unroll
        for (int j = 0; j < 4; ++j)
          m[mf][nf][j] = gelu_f(acc[mf][nf][j] + b1r[nf]);
  }
  #pragma unroll
  for (int mf = 0; mf < 4; ++mf)
    #pragma unroll
    for (int nf = 0; nf < 2; ++nf)
      #pragma unroll
      for (int j = 0; j < 4; ++j) {
        int row = 16 * mf + g * 4 + j;
        int col = cH + 16 * nf;
        *(f16*)(hB + row * 512 + ((col * 2) ^ ((row & 7) << 4))) = (f16)m[mf][nf][j];
      }
  __syncthreads();

  // ---- layer 2: h @ W2 ----
  {
    f4 acc[4][2];
    #pragma unroll
    for (int mf = 0; mf < 4; ++mf)
      #pragma unroll
      for (int nf = 0; nf < 2; ++nf) acc[mf][nf] = zf;
    #pragma unroll
    for (int kk = 0; kk < 8; ++kk) {
      h8 bb[2];
      #pragma unroll
      for (int nf = 0; nf < 2; ++nf)
        bb[nf] = *(const h8*)(W2s + ((kk * 256 + cH + 16 * nf) << 5) + g * 8);
      #pragma unroll
      for (int mf = 0; mf < 4; ++mf) {
        h8 a = *(const h8*)(hB + (16 * mf + r) * 512 + ((kk * 64 + g16) ^ sw));
        #pragma unroll
        for (int nf = 0; nf < 2; ++nf)
          acc[mf][nf] = MFMA(a, bb[nf], acc[mf][nf]);
      }
    }
    #pragma unroll
    for (int mf = 0; mf < 4; ++mf)
      #pragma unroll
      for (int nf = 0; nf < 2; ++nf)
        #pragma unroll
        for (int j = 0; j < 4; ++j)
          m[mf][nf][j] = gelu_f(acc[mf][nf][j] + b2r[nf]);
  }
  __syncthreads();
  #pragma unroll
  for (int mf = 0; mf < 4; ++mf)
    #pragma unroll
    for (int nf = 0; nf < 2; ++nf)
      #pragma unroll
      for (int j = 0; j < 4; ++j) {
        int row = 16 * mf + g * 4 + j;
        int col = cH + 16 * nf;
        *(f16*)(hB + row * 512 + ((col * 2) ^ ((row & 7) << 4))) = (f16)m[mf][nf][j];
      }
  __syncthreads();

  // ---- stage Wf2 -> registers via LDS chunks (4 x 64KB through uB) ----
  h8 wB[16][2];
  #pragma unroll
  for (int c = 0; c < 4; ++c) {
    const char* src = (const char*)Wf2s + c * 65536 + wn * 1024 + ln * 16;
    char* dst = uB + wn * 1024;
    #pragma unroll
    for (int j = 0; j < 8; ++j)
      gload_lds16(src + j * 8192, dst + j * 8192);
    __syncthreads();
    #pragma unroll
    for (int k2 = 0; k2 < 4; ++k2)
      #pragma unroll
      for (int nf = 0; nf < 2; ++nf)
        wB[c * 4 + k2][nf] =
          *(const h8*)(uB + ((k2 * 256 + cH + 16 * nf) << 6) + g16);
    __syncthreads();
  }

  // ---- prime Wf1 ring (ring-4, distance-3); wave base is lane-linear ----
  const f16* wf1w = Wf1s + (4 * wn) * 512 + ln * 8;
  h8 pf[4][2];
  #pragma unroll
  for (int p = 0; p < 3; ++p)
    #pragma unroll
    for (int nf = 0; nf < 2; ++nf)
      pf[p][nf] = *(const h8*)(wf1w + (((p & 7) * 32 + 2 * (p >> 3) + nf) << 9));

  // ---- 48 fractal steps ----
  for (int t = 0; t < TSTEPS; ++t) {
    // GEMM1: u = h @ Wf1 (N=512), wave cols [64*wn,+64) in two 32-col halves
    #pragma unroll
    for (int q = 0; q < 2; ++q) {
      f4 acc[4][2];
      #pragma unroll
      for (int mf = 0; mf < 4; ++mf)
        #pragma unroll
        for (int nf = 0; nf < 2; ++nf) acc[mf][nf] = zf;
      #pragma unroll
      for (int kk = 0; kk < 8; ++kk) {
        const int i = q * 8 + kk;
        const int ip = (i + 3) & 15;
        #pragma unroll
        for (int nf = 0; nf < 2; ++nf)
          pf[(i + 3) & 3][nf] =
            *(const h8*)(wf1w + (((ip & 7) * 32 + 2 * (ip >> 3) + nf) << 9));
        #pragma unroll
        for (int mf = 0; mf < 4; ++mf) {
          h8 a = *(const h8*)(hB + (16 * mf + r) * 512 + ((kk * 64 + g16) ^ sw));
          #pragma unroll
          for (int nf = 0; nf < 2; ++nf)
            acc[mf][nf] = MFMA(a, pf[i & 3][nf], acc[mf][nf]);
        }
      }
      #pragma unroll
      for (int mf = 0; mf < 4; ++mf)
        #pragma unroll
        for (int nf = 0; nf < 2; ++nf)
          #pragma unroll
          for (int j = 0; j < 4; ++j) {
            float gv = gelu_f(acc[mf][nf][j] + bf1r[q * 2 + nf]);
            int row = 16 * mf + g * 4 + j;
            int col = 64 * wn + 32 * q + 16 * nf + r;
            *(f16*)(uB + row * 1024 + ((col * 2) ^ ((row & 7) << 4))) = (f16)gv;
          }
    }
    __syncthreads();

    // GEMM2: h' = tanh(u @ Wf2) — B entirely in registers (zero loads)
    f4 a2[4][2];
    #pragma unroll
    for (int mf = 0; mf < 4; ++mf)
      #pragma unroll
      for (int nf = 0; nf < 2; ++nf) a2[mf][nf] = zf;
    #pragma unroll
    for (int kk = 0; kk < 16; ++kk) {
      #pragma unroll
      for (int mf = 0; mf < 4; ++mf) {
        h8 a = *(const h8*)(uB + (16 * mf + r) * 1024 + ((kk * 64 + g16) ^ sw));
        #pragma unroll
        for (int nf = 0; nf < 2; ++nf)
          a2[mf][nf] = MFMA(a, wB[kk][nf], a2[mf][nf]);
      }
    }
    #pragma unroll
    for (int mf = 0; mf < 4; ++mf)
      #pragma unroll
      for (int nf = 0; nf < 2; ++nf)
        #pragma unroll
        for (int j = 0; j < 4; ++j) {
          float u = tanh_f(a2[mf][nf][j] + bf2r[nf]);
          float hn = 0.5f * (m[mf][nf][j] + u);
          m[mf][nf][j] = hn;
          int row = 16 * mf + g * 4 + j;
          int col = cH + 16 * nf;
          *(f16*)(hB + row * 512 + ((col * 2) ^ ((row & 7) << 4))) = (f16)hn;
        }
    __syncthreads();
  }

  // ---- final: out = h @ Wo + bo ----
  {
    f4 acc[4][2];
    #pragma unroll
    for (int mf = 0; mf < 4; ++mf)
      #pragma unroll
      for (int nf = 0; nf < 2; ++nf) acc[mf][nf] = zf;
    #pragma unroll
    for (int kk = 0; kk < 8; ++kk) {
      h8 bb[2];
      #pragma unroll
      for (int nf = 0; nf < 2; ++nf)
        bb[nf] = *(const h8*)(Wos + ((kk * 256 + cH + 16 * nf) << 5) + g * 8);
      #pragma unroll
      for (int mf = 0; mf < 4; ++mf) {
        h8 a = *(const h8*)(hB + (16 * mf + r) * 512 + ((kk * 64 + g16) ^ sw));
        #pragma unroll
        for (int nf = 0; nf < 2; ++nf)
          acc[mf][nf] = MFMA(a, bb[nf], acc[mf][nf]);
      }
    }
    #pragma unroll
    for (int mf = 0; mf < 4; ++mf)
      #pragma unroll
      for (int nf = 0; nf < 2; ++nf)
        #pragma unroll
        for (int j = 0; j < 4; ++j) {
          int row = row0 + 16 * mf + g * 4 + j;
          int col = cH + 16 * nf;
          out[(size_t)row * 256 + col] = acc[mf][nf][j] + bor[nf];
        }
  }
}

// ---------------- host launch ----------------
extern "C" void kernel_launch(void* const* d_in, const int* in_sizes, int n_in,
                              void* d_out, int out_size, void* d_ws, size_t ws_size,
                              hipStream_t stream) {
  const float* x      = (const float*)d_in[0];
  const float* z      = (const float*)d_in[1];
  const float* tables = (const float*)d_in[2];
  const float* W1     = (const float*)d_in[3];
  const float* b1     = (const float*)d_in[4];
  const float* W2     = (const float*)d_in[5];
  const float* b2     = (const float*)d_in[6];
  const float* Wf1    = (const float*)d_in[7];
  const float* bf1    = (const float*)d_in[8];
  const float* Wf2    = (const float*)d_in[9];
  const float* bf2    = (const float*)d_in[10];
  const float* Wo     = (const float*)d_in[11];
  const float* bo     = (const float*)d_in[12];
  const int*   res    = (const int*)d_in[13];
  const float* freqs  = (const float*)d_in[14];
  float* out = (float*)d_out;

  char* ws = (char*)d_ws;
  f16* featsH = (f16*)(ws);                 // 16384*192*2 = 6291456
  f16* W1s    = (f16*)(ws + 6291456);       // 98304
  f16* W2s    = (f16*)(ws + 6389760);       // 131072
  f16* Wos    = (f16*)(ws + 6520832);       // 131072
  f16* Wf1s   = (f16*)(ws + 6651904);       // 262144 (lane-linear frags)
  f16* Wf2s   = (f16*)(ws + 6914048);       // 262144 (k-slice stream)

  prep_ws<<<192, 256, 0, stream>>>(W1,  W1s,  161, 256, 6  * 256 * 32);
  prep_ws<<<256, 256, 0, stream>>>(W2,  W2s,  256, 256, 8  * 256 * 32);
  prep_ws<<<256, 256, 0, stream>>>(Wo,  Wos,  256, 256, 8  * 256 * 32);
  prep_wf1lin<<<512, 256, 0, stream>>>(Wf1, Wf1s);
  prep_ws<<<512, 256, 0, stream>>>(Wf2, Wf2s, 512, 256, 16 * 256 * 32);
  feat_kernel<<<256, 64, 0, stream>>>(x, z, tables, res, freqs, featsH);

  (void)hipFuncSetAttribute((const void*)fractal_main,
                            hipFuncAttributeMaxDynamicSharedMemorySize, 98304);
  fractal_main<<<256, 512, 98304, stream>>>(featsH, W1s, W2s, Wos, Wf1s, Wf2s,
                                            b1, b2, bf1, bf2, bo, out);
}

// Round 7
// 1978.956 us; speedup vs baseline: 1.1017x; 1.0015x over previous
//
#include <hip/hip_runtime.h>
#include <hip/hip_fp16.h>
#include <math.h>
#include <stdint.h>

typedef _Float16 f16;
typedef _Float16 h8 __attribute__((ext_vector_type(8)));
typedef float f4 __attribute__((ext_vector_type(4)));

#define TSTEPS 48

#define MFMA(a,b,c) __builtin_amdgcn_mfma_f32_16x16x32_f16((a),(b),(c),0,0,0)

__device__ __forceinline__ float gelu_f(float x) {
  float ax = fabsf(x) * 0.7071067811865475f;
  float t = __builtin_amdgcn_rcpf(1.0f + 0.3275911f * ax);
  float poly = t * (0.254829592f + t * (-0.284496736f + t * (1.421413741f +
               t * (-1.453152027f + t * 1.061405429f))));
  float e = exp2f(-ax * ax * 1.4426950408889634f);
  float er = copysignf(1.0f - poly * e, x);
  return 0.5f * x * (1.0f + er);
}

__device__ __forceinline__ float tanh_f(float x) {
  float e = exp2f(x * 2.885390081777927f);
  return 1.0f - 2.0f * __builtin_amdgcn_rcpf(e + 1.0f);
}

__device__ __forceinline__ void gload_lds16(const void* g, void* l) {
  __builtin_amdgcn_global_load_lds(
      (const __attribute__((address_space(1))) void*)g,
      (__attribute__((address_space(3))) void*)l, 16, 0, 0);
}

// ---------------- weight prep: k-slice stream  dst[(kk*N+n)*32+w] = src[(kk*32+w)*N+n]
__global__ void prep_ws(const float* __restrict__ src, f16* __restrict__ dst,
                        int Kreal, int N, int total) {
  int idx = blockIdx.x * 256 + threadIdx.x;
  if (idx >= total) return;
  int w = idx & 31;
  int n = (idx >> 5) % N;
  int kk = idx / (N * 32);
  int k = kk * 32 + w;
  dst[idx] = (f16)((k < Kreal) ? src[k * N + n] : 0.f);
}

// ---------------- Wf1 lane-linear fragment stream ----------------
__global__ void prep_wf1lin(const float* __restrict__ src, f16* __restrict__ dst) {
  int idx = blockIdx.x * 256 + threadIdx.x;   // 131072 elems
  if (idx >= 131072) return;
  int fragid = idx >> 9;        // 0..255
  int within = idx & 511;
  int ln = within >> 3, e = within & 7;
  int kk = fragid >> 5, cf = fragid & 31;
  int k = kk * 32 + (ln >> 4) * 8 + e;
  int n = cf * 16 + (ln & 15);
  dst[idx] = (f16)src[k * 512 + n];
}

// ---------------- feature kernel: fourier + hashgrid + z -> fp16 [B][192] ----
__global__ void feat_kernel(const float* __restrict__ x, const float* __restrict__ z,
                            const float* __restrict__ tables, const int* __restrict__ res,
                            const float* __restrict__ freqs, f16* __restrict__ featsH) {
  __shared__ f16 rowbuf[64][194];
  const int t = threadIdx.x;        // 64 threads
  const int b = blockIdx.x;
  const int i = b * 64 + t;

  float xv = x[i];
  float xn = fminf(fmaxf(xv, 0.f), 1.f);
  f16* dst = rowbuf[t];
  dst[0] = (f16)xn;
  float w2pi = 6.283185307179586f * xn;
  #pragma unroll
  for (int k = 0; k < 32; ++k) {
    float a = w2pi * freqs[k];
    float s, c;
    sincosf(a, &s, &c);
    dst[1 + k]  = (f16)s;
    dst[33 + k] = (f16)c;
  }
  #pragma unroll
  for (int l = 0; l < 8; ++l) {
    int R = res[l];
    int Rm1 = R - 1;
    float tt = xn * (float)Rm1;
    int i0 = (int)tt;
    int i1 = min(i0 + 1, Rm1);
    float w = tt - (float)i0;
    uint32_t lt = (uint32_t)(l * 19349663);
    uint32_t h0 = (((uint32_t)i0 * 73856093u) ^ lt) & 16383u;
    uint32_t h1 = (((uint32_t)i1 * 73856093u) ^ lt) & 16383u;
    const float* e0 = tables + ((size_t)l * 16384 + h0) * 8;
    const float* e1 = tables + ((size_t)l * 16384 + h1) * 8;
    #pragma unroll
    for (int e = 0; e < 8; ++e) {
      float v = e0[e] * (1.f - w) + e1[e] * w;
      dst[65 + l * 8 + e] = (f16)v;
    }
  }
  #pragma unroll
  for (int j = 0; j < 32; ++j) dst[129 + j] = (f16)z[(size_t)i * 32 + j];
  #pragma unroll
  for (int j = 161; j < 192; ++j) dst[j] = (f16)0.f;

  __syncthreads();
  uint32_t* dg = (uint32_t*)(featsH + (size_t)b * 64 * 192);
  for (int idx = t; idx < 64 * 96; idx += 64) {
    int row = idx / 96, o = idx - row * 96;
    dg[idx] = ((const uint32_t*)&rowbuf[row][0])[o];
  }
}

// ---------------- main fused kernel ----------------
// 256 blocks x 512 threads (8 waves), 1 block/CU (LDS 96KB), 2 waves/SIMD.
// __launch_bounds__(512,1): 2nd arg is min BLOCKS/CU (CUDA semantics on hipcc;
// (512,2) capped VGPR at 128 and (1024,4) at 64 in prior rounds -> spills ->
// scratch thrashed per-XCD L2 -> weight stream missed). With 1: cap 256.
// Wf2 wave slice (32 x h8 = 128 VGPR) register-resident, loaded once via LDS.
// Wf1 streamed lane-linear, ring-4 distance-3 register prefetch, L2-resident.
__global__ __launch_bounds__(512, 1) void fractal_main(
    const f16* __restrict__ featsH,
    const f16* __restrict__ W1s, const f16* __restrict__ W2s,
    const f16* __restrict__ Wos,
    const f16* __restrict__ Wf1s, const f16* __restrict__ Wf2s,
    const float* __restrict__ b1, const float* __restrict__ b2,
    const float* __restrict__ bf1, const float* __restrict__ bf2,
    const float* __restrict__ bo,
    float* __restrict__ out) {
  extern __shared__ char smem[];
  char* hB = smem;            // 32KB
  char* uB = smem + 32768;    // 64KB

  const int tid = threadIdx.x;
  const int wn  = tid >> 6;          // 0..7
  const int ln  = tid & 63;
  const int r   = ln & 15;
  const int g   = ln >> 4;
  const int sw  = (r & 7) << 4;
  const int g16 = g * 16;
  const int row0 = blockIdx.x * 64;

  const int cH = 32 * wn + r;        // wave's HID-col base (+16*nf)
  float b1r[2], b2r[2], bf2r[2], bor[2], bf1r[4];
  #pragma unroll
  for (int nf = 0; nf < 2; ++nf) {
    b1r[nf] = b1[cH + 16 * nf]; b2r[nf] = b2[cH + 16 * nf];
    bf2r[nf] = bf2[cH + 16 * nf]; bor[nf] = bo[cH + 16 * nf];
  }
  #pragma unroll
  for (int nf = 0; nf < 4; ++nf) bf1r[nf] = bf1[64 * wn + 16 * nf + r];

  // ---- stage feats tile into uB (swizzled, row stride 384B) ----
  {
    const char* src = (const char*)featsH + (size_t)row0 * 384;
    for (int i = tid; i < 6144; i += 512) {
      int row = i / 96;
      int off = (i - row * 96) * 4;
      uint32_t v = *(const uint32_t*)(src + (size_t)i * 4);
      *(uint32_t*)(uB + row * 384 + (off ^ ((row & 7) << 4))) = v;
    }
  }
  __syncthreads();

  f4 m[4][2];   // master h (f32), rows 16*mf+g*4+j, cols cH+16*nf
  const f4 zf = {0.f, 0.f, 0.f, 0.f};

  // ---- layer 1: feats @ W1 ----
  {
    f4 acc[4][2];
    #pragma unroll
    for (int mf = 0; mf < 4; ++mf)
      #pragma unroll
      for (int nf = 0; nf < 2; ++nf) acc[mf][nf] = zf;
    #pragma unroll
    for (int kk = 0; kk < 6; ++kk) {
      h8 bb[2];
      #pragma unroll
      for (int nf = 0; nf < 2; ++nf)
        bb[nf] = *(const h8*)(W1s + ((kk * 256 + cH + 16 * nf) << 5) + g * 8);
      #pragma unroll
      for (int mf = 0; mf < 4; ++mf) {
        h8 a = *(const h8*)(uB + (16 * mf + r) * 384 + ((kk * 64 + g16) ^ sw));
        #pragma unroll
        for (int nf = 0; nf < 2; ++nf)
          acc[mf][nf] = MFMA(a, bb[nf], acc[mf][nf]);
      }
    }
    #pragma unroll
    for (int mf = 0; mf < 4; ++mf)
      #pragma unroll
      for (int nf = 0; nf < 2; ++nf)
        #pragma unroll
        for (int j = 0; j < 4; ++j)
          m[mf][nf][j] = gelu_f(acc[mf][nf][j] + b1r[nf]);
  }
  #pragma unroll
  for (int mf = 0; mf < 4; ++mf)
    #pragma unroll
    for (int nf = 0; nf < 2; ++nf)
      #pragma unroll
      for (int j = 0; j < 4; ++j) {
        int row = 16 * mf + g * 4 + j;
        int col = cH + 16 * nf;
        *(f16*)(hB + row * 512 + ((col * 2) ^ ((row & 7) << 4))) = (f16)m[mf][nf][j];
      }
  __syncthreads();

  // ---- layer 2: h @ W2 ----
  {
    f4 acc[4][2];
    #pragma unroll
    for (int mf = 0; mf < 4; ++mf)
      #pragma unroll
      for (int nf = 0; nf < 2; ++nf) acc[mf][nf] = zf;
    #pragma unroll
    for (int kk = 0; kk < 8; ++kk) {
      h8 bb[2];
      #pragma unroll
      for (int nf = 0; nf < 2; ++nf)
        bb[nf] = *(const h8*)(W2s + ((kk * 256 + cH + 16 * nf) << 5) + g * 8);
      #pragma unroll
      for (int mf = 0; mf < 4; ++mf) {
        h8 a = *(const h8*)(hB + (16 * mf + r) * 512 + ((kk * 64 + g16) ^ sw));
        #pragma unroll
        for (int nf = 0; nf < 2; ++nf)
          acc[mf][nf] = MFMA(a, bb[nf], acc[mf][nf]);
      }
    }
    #pragma unroll
    for (int mf = 0; mf < 4; ++mf)
      #pragma unroll
      for (int nf = 0; nf < 2; ++nf)
        #pragma unroll
        for (int j = 0; j < 4; ++j)
          m[mf][nf][j] = gelu_f(acc[mf][nf][j] + b2r[nf]);
  }
  __syncthreads();
  #pragma unroll
  for (int mf = 0; mf < 4; ++mf)
    #pragma unroll
    for (int nf = 0; nf < 2; ++nf)
      #pragma unroll
      for (int j = 0; j < 4; ++j) {
        int row = 16 * mf + g * 4 + j;
        int col = cH + 16 * nf;
        *(f16*)(hB + row * 512 + ((col * 2) ^ ((row & 7) << 4))) = (f16)m[mf][nf][j];
      }
  __syncthreads();

  // ---- stage Wf2 -> registers via LDS chunks (4 x 64KB through uB) ----
  h8 wB[16][2];
  #pragma unroll
  for (int c = 0; c < 4; ++c) {
    const char* src = (const char*)Wf2s + c * 65536 + wn * 1024 + ln * 16;
    char* dst = uB + wn * 1024;
    #pragma unroll
    for (int j = 0; j < 8; ++j)
      gload_lds16(src + j * 8192, dst + j * 8192);
    __syncthreads();
    #pragma unroll
    for (int k2 = 0; k2 < 4; ++k2)
      #pragma unroll
      for (int nf = 0; nf < 2; ++nf)
        wB[c * 4 + k2][nf] =
          *(const h8*)(uB + ((k2 * 256 + cH + 16 * nf) << 6) + g16);
    __syncthreads();
  }

  // ---- prime Wf1 ring (ring-4, distance-3); wave base is lane-linear ----
  const f16* wf1w = Wf1s + (4 * wn) * 512 + ln * 8;
  h8 pf[4][2];
  #pragma unroll
  for (int p = 0; p < 3; ++p)
    #pragma unroll
    for (int nf = 0; nf < 2; ++nf)
      pf[p][nf] = *(const h8*)(wf1w + (((p & 7) * 32 + 2 * (p >> 3) + nf) << 9));

  // ---- 48 fractal steps ----
  for (int t = 0; t < TSTEPS; ++t) {
    // GEMM1: u = h @ Wf1 (N=512), wave cols [64*wn,+64) in two 32-col halves
    #pragma unroll
    for (int q = 0; q < 2; ++q) {
      f4 acc[4][2];
      #pragma unroll
      for (int mf = 0; mf < 4; ++mf)
        #pragma unroll
        for (int nf = 0; nf < 2; ++nf) acc[mf][nf] = zf;
      #pragma unroll
      for (int kk = 0; kk < 8; ++kk) {
        const int i = q * 8 + kk;
        const int ip = (i + 3) & 15;
        #pragma unroll
        for (int nf = 0; nf < 2; ++nf)
          pf[(i + 3) & 3][nf] =
            *(const h8*)(wf1w + (((ip & 7) * 32 + 2 * (ip >> 3) + nf) << 9));
        #pragma unroll
        for (int mf = 0; mf < 4; ++mf) {
          h8 a = *(const h8*)(hB + (16 * mf + r) * 512 + ((kk * 64 + g16) ^ sw));
          #pragma unroll
          for (int nf = 0; nf < 2; ++nf)
            acc[mf][nf] = MFMA(a, pf[i & 3][nf], acc[mf][nf]);
        }
      }
      #pragma unroll
      for (int mf = 0; mf < 4; ++mf)
        #pragma unroll
        for (int nf = 0; nf < 2; ++nf)
          #pragma unroll
          for (int j = 0; j < 4; ++j) {
            float gv = gelu_f(acc[mf][nf][j] + bf1r[q * 2 + nf]);
            int row = 16 * mf + g * 4 + j;
            int col = 64 * wn + 32 * q + 16 * nf + r;
            *(f16*)(uB + row * 1024 + ((col * 2) ^ ((row & 7) << 4))) = (f16)gv;
          }
    }
    __syncthreads();

    // GEMM2: h' = tanh(u @ Wf2) — B entirely in registers (zero loads)
    f4 a2[4][2];
    #pragma unroll
    for (int mf = 0; mf < 4; ++mf)
      #pragma unroll
      for (int nf = 0; nf < 2; ++nf) a2[mf][nf] = zf;
    #pragma unroll
    for (int kk = 0; kk < 16; ++kk) {
      #pragma unroll
      for (int mf = 0; mf < 4; ++mf) {
        h8 a = *(const h8*)(uB + (16 * mf + r) * 1024 + ((kk * 64 + g16) ^ sw));
        #pragma unroll
        for (int nf = 0; nf < 2; ++nf)
          a2[mf][nf] = MFMA(a, wB[kk][nf], a2[mf][nf]);
      }
    }
    #pragma unroll
    for (int mf = 0; mf < 4; ++mf)
      #pragma unroll
      for (int nf = 0; nf < 2; ++nf)
        #pragma unroll
        for (int j = 0; j < 4; ++j) {
          float u = tanh_f(a2[mf][nf][j] + bf2r[nf]);
          float hn = 0.5f * (m[mf][nf][j] + u);
          m[mf][nf][j] = hn;
          int row = 16 * mf + g * 4 + j;
          int col = cH + 16 * nf;
          *(f16*)(hB + row * 512 + ((col * 2) ^ ((row & 7) << 4))) = (f16)hn;
        }
    __syncthreads();
  }

  // ---- final: out = h @ Wo + bo ----
  {
    f4 acc[4][2];
    #pragma unroll
    for (int mf = 0; mf < 4; ++mf)
      #pragma unroll
      for (int nf = 0; nf < 2; ++nf) acc[mf][nf] = zf;
    #pragma unroll
    for (int kk = 0; kk < 8; ++kk) {
      h8 bb[2];
      #pragma unroll
      for (int nf = 0; nf < 2; ++nf)
        bb[nf] = *(const h8*)(Wos + ((kk * 256 + cH + 16 * nf) << 5) + g * 8);
      #pragma unroll
      for (int mf = 0; mf < 4; ++mf) {
        h8 a = *(const h8*)(hB + (16 * mf + r) * 512 + ((kk * 64 + g16) ^ sw));
        #pragma unroll
        for (int nf = 0; nf < 2; ++nf)
          acc[mf][nf] = MFMA(a, bb[nf], acc[mf][nf]);
      }
    }
    #pragma unroll
    for (int mf = 0; mf < 4; ++mf)
      #pragma unroll
      for (int nf = 0; nf < 2; ++nf)
        #pragma unroll
        for (int j = 0; j < 4; ++j) {
          int row = row0 + 16 * mf + g * 4 + j;
          int col = cH + 16 * nf;
          out[(size_t)row * 256 + col] = acc[mf][nf][j] + bor[nf];
        }
  }
}

// ---------------- host launch ----------------
extern "C" void kernel_launch(void* const* d_in, const int* in_sizes, int n_in,
                              void* d_out, int out_size, void* d_ws, size_t ws_size,
                              hipStream_t stream) {
  const float* x      = (const float*)d_in[0];
  const float* z      = (const float*)d_in[1];
  const float* tables = (const float*)d_in[2];
  const float* W1     = (const float*)d_in[3];
  const float* b1     = (const float*)d_in[4];
  const float* W2     = (const float*)d_in[5];
  const float* b2     = (const float*)d_in[6];
  const float* Wf1    = (const float*)d_in[7];
  const float* bf1    = (const float*)d_in[8];
  const float* Wf2    = (const float*)d_in[9];
  const float* bf2    = (const float*)d_in[10];
  const float* Wo     = (const float*)d_in[11];
  const float* bo     = (const float*)d_in[12];
  const int*   res    = (const int*)d_in[13];
  const float* freqs  = (const float*)d_in[14];
  float* out = (float*)d_out;

  char* ws = (char*)d_ws;
  f16* featsH = (f16*)(ws);                 // 16384*192*2 = 6291456
  f16* W1s    = (f16*)(ws + 6291456);       // 98304
  f16* W2s    = (f16*)(ws + 6389760);       // 131072
  f16* Wos    = (f16*)(ws + 6520832);       // 131072
  f16* Wf1s   = (f16*)(ws + 6651904);       // 262144 (lane-linear frags)
  f16* Wf2s   = (f16*)(ws + 6914048);       // 262144 (k-slice stream)

  prep_ws<<<192, 256, 0, stream>>>(W1,  W1s,  161, 256, 6  * 256 * 32);
  prep_ws<<<256, 256, 0, stream>>>(W2,  W2s,  256, 256, 8  * 256 * 32);
  prep_ws<<<256, 256, 0, stream>>>(Wo,  Wos,  256, 256, 8  * 256 * 32);
  prep_wf1lin<<<512, 256, 0, stream>>>(Wf1, Wf1s);
  prep_ws<<<512, 256, 0, stream>>>(Wf2, Wf2s, 512, 256, 16 * 256 * 32);
  feat_kernel<<<256, 64, 0, stream>>>(x, z, tables, res, freqs, featsH);

  (void)hipFuncSetAttribute((const void*)fractal_main,
                            hipFuncAttributeMaxDynamicSharedMemorySize, 98304);
  fractal_main<<<256, 512, 98304, stream>>>(featsH, W1s, W2s, Wos, Wf1s, Wf2s,
                                            b1, b2, bf1, bf2, bo, out);
}